// Round 12
// baseline (1779.881 us; speedup 1.0000x reference)
//
#include <hip/hip_runtime.h>
#include <math.h>

#define N_NODES 50000
#define N_EDGES 640000
#define FDIM 128
#define NCLS 16
#define BN_EPS 1e-5f
#define NBS 196            // scan blocks
#define NBG 782            // gemm tiles
#define NBC 625            // count blocks
#define NBF 313            // fill blocks (grid-strided x2)
#define NBA1 12500         // agg1 blocks
#define NBA2 3125          // agg2 blocks

// ctl indices (x32 ints = 128B apart -> separate cache lines)
#define CTL_CCNT 0         // count done counter
#define CTL_CFLG 32        // count done flag
#define CTL_SCNT 64        // scan done counter
#define CTL_SFLG 96        // scan done flag
#define CTL_ACNT 128       // agg1 done counter
#define CTL_AFLG 160       // agg1 done flag

typedef __attribute__((ext_vector_type(8))) short bf16x8;
typedef __attribute__((ext_vector_type(4))) float f32x4;

// ---- bf16 pack/unpack (RNE) ----
__device__ __forceinline__ unsigned pack_bf16x2(float lo, float hi) {
    unsigned ul = __float_as_uint(lo);
    unsigned uh = __float_as_uint(hi);
    ul += 0x7fff + ((ul >> 16) & 1);
    uh += 0x7fff + ((uh >> 16) & 1);
    return (ul >> 16) | (uh & 0xffff0000u);
}
__device__ __forceinline__ unsigned short bf16_rne(float x) {
    unsigned u = __float_as_uint(x);
    u += 0x7fff + ((u >> 16) & 1);
    return (unsigned short)(u >> 16);
}
__device__ __forceinline__ float bf_lo(unsigned u) { return __uint_as_float(u << 16); }
__device__ __forceinline__ float bf_hi(unsigned u) { return __uint_as_float(u & 0xffff0000u); }

// relaxed RMW poll: coherent-point read, NO cache invalidation per poll (R11's failure was
// ACQUIRE polls -> buffer_inv storm). Acquire happens once, after the flag flips.
__device__ __forceinline__ void poll_flag(int* p) {
    while (__hip_atomic_fetch_add(p, 0, __ATOMIC_RELAXED, __HIP_MEMORY_SCOPE_AGENT) == 0)
        __builtin_amdgcn_s_sleep(32);
}
// producer completion: release fence, count, last one sets the flag (separate line)
__device__ __forceinline__ void finish_stage(int* cnt, int* flg, int total, int tid) {
    __threadfence();
    if (tid == 0) {
        int old = __hip_atomic_fetch_add(cnt, 1, __ATOMIC_ACQ_REL, __HIP_MEMORY_SCOPE_AGENT);
        if (old == total - 1)
            __hip_atomic_store(flg, 1, __ATOMIC_RELEASE, __HIP_MEMORY_SCOPE_AGENT);
    }
}

// ============ K0: fold (0..7) | W1 hi/lo pack (8..15) | zero deg+ctl ============
__global__ __launch_bounds__(256) void packw_fold_zero_kernel(
        const float* __restrict__ W1,
        const float* __restrict__ W2, const float* __restrict__ Wc,
        const float* __restrict__ b1, const float* __restrict__ b2,
        const float* __restrict__ bc, const float* __restrict__ gamma,
        const float* __restrict__ beta, const float* __restrict__ rmean,
        const float* __restrict__ rvar,
        bf16x8* __restrict__ WHg, bf16x8* __restrict__ WLg,
        float* __restrict__ W2c, float* __restrict__ bc2, float4* __restrict__ fusedq,
        int* __restrict__ deg, int* __restrict__ ctl) {
    int tid = threadIdx.x;
    int bid = blockIdx.x;
    for (int i = bid * 256 + tid; i < N_NODES; i += 16 * 256) deg[i] = 0;
    if (bid == 0) ctl[tid] = 0;

    if (bid < 8) {
        int gid = bid * 256 + tid;                 // 0..2047
        int r = gid >> 4, c = gid & 15;
        float acc = 0.f;
#pragma unroll 8
        for (int k = 0; k < 128; k++) acc += W2[r * 128 + k] * Wc[k * 16 + c];
        W2c[gid] = acc;
        if (bid == 0) {
            if (tid < 16) {
                float a = bc[tid];
                for (int k = 0; k < 128; k++) a += b2[k] * Wc[k * 16 + tid];
                bc2[tid] = a;
            }
            if (tid < 64) {
                int c0 = tid * 2, c1 = c0 + 1;
                float sc0 = gamma[c0] * rsqrtf(rvar[c0] + BN_EPS);
                float sc1 = gamma[c1] * rsqrtf(rvar[c1] + BN_EPS);
                float sh0 = (b1[c0] - rmean[c0]) * sc0 + beta[c0];
                float sh1 = (b1[c1] - rmean[c1]) * sc1 + beta[c1];
                fusedq[tid] = make_float4(sc0, sh0, sc1, sh1);
            }
        }
    } else {
        int fi = (bid - 8) * 256 + tid;            // fragment index 0..2047
        int lane = fi & 63, kt = (fi >> 6) & 3, ct = fi >> 8;
        int kbase = kt * 32 + (lane >> 4) * 8;
        int col = ct * 16 + (lane & 15);
        short h[8], lo[8];
#pragma unroll
        for (int j = 0; j < 8; j++) {
            float wv = W1[(kbase + j) * 128 + col];
            unsigned short hs = bf16_rne(wv);
            float rem = wv - __uint_as_float(((unsigned)hs) << 16);
            h[j] = (short)hs;
            lo[j] = (short)bf16_rne(rem);
        }
        WHg[fi] = *(bf16x8*)h;
        WLg[fi] = *(bf16x8*)lo;
    }
}

// ============ K1: gemm (0..781) | count (782..1406) | scan (poll) | fill (poll) ============
__global__ __launch_bounds__(256) void gemm_csr_kernel(
        const float* __restrict__ seq,
        const bf16x8* __restrict__ WHg, const bf16x8* __restrict__ WLg,
        unsigned* __restrict__ bufA,
        const int* __restrict__ eidx,
        int* __restrict__ deg, int* __restrict__ cursor,
        int* __restrict__ offs, int* __restrict__ partials,
        float* __restrict__ dinv, int2* __restrict__ csr_sw,
        int* __restrict__ ctl) {
    __shared__ __align__(16) char smem[64 * 132 * 4];
    int tid = threadIdx.x;
    int bid = blockIdx.x;

    if (bid < NBG) {
        // ---------------- MFMA gemm tile: 64 rows, 4 waves x 16 rows ----------------
        float* sC = (float*)smem;
        int w = tid >> 6, l = tid & 63;
        int la = l & 15, q = l >> 4;
        int r0 = bid * 64;
        int arow = r0 + w * 16 + la;
        bool rowok = arow < N_NODES;
        const float4* X4 = (const float4*)seq;

        float4 xr[8];
#pragma unroll
        for (int kt = 0; kt < 4; kt++) {
            float4 z4 = make_float4(0.f, 0.f, 0.f, 0.f);
            xr[kt * 2]     = rowok ? X4[arow * 32 + kt * 8 + q * 2]     : z4;
            xr[kt * 2 + 1] = rowok ? X4[arow * 32 + kt * 8 + q * 2 + 1] : z4;
        }
        bf16x8 ah[4], al[4];
#pragma unroll
        for (int kt = 0; kt < 4; kt++) {
            const float* xv = (const float*)&xr[kt * 2];
#pragma unroll
            for (int j = 0; j < 8; j++) {
                float v = xv[j];
                unsigned short hs = bf16_rne(v);
                float rem = v - __uint_as_float(((unsigned)hs) << 16);
                ah[kt][j] = (short)hs;
                al[kt][j] = (short)bf16_rne(rem);
            }
        }
        f32x4 acc[8];
#pragma unroll
        for (int ct = 0; ct < 8; ct++) acc[ct] = (f32x4){0.f, 0.f, 0.f, 0.f};
#pragma unroll
        for (int kt = 0; kt < 4; kt++) {
#pragma unroll
            for (int ct = 0; ct < 8; ct++) {
                bf16x8 bh = WHg[(ct * 4 + kt) * 64 + l];   // coalesced b128, L2-hot
                bf16x8 bl = WLg[(ct * 4 + kt) * 64 + l];
                acc[ct] = __builtin_amdgcn_mfma_f32_16x16x32_bf16(ah[kt], bh, acc[ct], 0, 0, 0);
                acc[ct] = __builtin_amdgcn_mfma_f32_16x16x32_bf16(ah[kt], bl, acc[ct], 0, 0, 0);
                acc[ct] = __builtin_amdgcn_mfma_f32_16x16x32_bf16(al[kt], bh, acc[ct], 0, 0, 0);
            }
        }
#pragma unroll
        for (int ct = 0; ct < 8; ct++)
#pragma unroll
            for (int r = 0; r < 4; r++)
                sC[(w * 16 + q * 4 + r) * 132 + ct * 16 + la] = acc[ct][r];
        __syncthreads();
        int trow = tid >> 2, tcb = (tid & 3) * 32;
        int grow = r0 + trow;
        if (grow < N_NODES) {
            const float4* sr4 = (const float4*)(sC + trow * 132 + tcb);
            unsigned ob[16];
#pragma unroll
            for (int t = 0; t < 8; t++) {
                float4 v = sr4[t];
                ob[2 * t]     = pack_bf16x2(v.x, v.y);
                ob[2 * t + 1] = pack_bf16x2(v.z, v.w);
            }
            uint4* dp = (uint4*)(bufA + (size_t)grow * 64 + (tid & 3) * 16);
#pragma unroll
            for (int g = 0; g < 4; g++)
                dp[g] = make_uint4(ob[g * 4], ob[g * 4 + 1], ob[g * 4 + 2], ob[g * 4 + 3]);
        }
    } else if (bid < NBG + NBC) {
        // ---------------- count in-degrees ----------------
        const int4* dst4 = (const int4*)(eidx + N_EDGES);
        int t = (bid - NBG) * 256 + tid;
        int4 d = dst4[t];
        atomicAdd(&deg[d.x], 1);
        atomicAdd(&deg[d.y], 1);
        atomicAdd(&deg[d.z], 1);
        atomicAdd(&deg[d.w], 1);
        finish_stage(&ctl[CTL_CCNT], &ctl[CTL_CFLG], NBC, tid);
    } else if (bid < NBG + NBC + NBS) {
        // ---------------- scan (poll count flag) ----------------
        int* s = (int*)smem;
        __shared__ int isLast;
        int sb = bid - (NBG + NBC);
        if (tid == 0) poll_flag(&ctl[CTL_CFLG]);
        __syncthreads();
        __threadfence();                           // acquire: fresh deg
        int gid = sb * 256 + tid;
        int v = (gid < N_NODES) ? deg[gid] : 0;
        if (gid < N_NODES) {
            dinv[gid] = rsqrtf((float)(v + 1));    // +1 self loop
            cursor[gid] = 0;
        }
        s[tid] = v;
        __syncthreads();
        for (int off = 1; off < 256; off <<= 1) {
            int t2 = (tid >= off) ? s[tid - off] : 0;
            __syncthreads();
            s[tid] += t2;
            __syncthreads();
        }
        if (gid <= N_NODES) offs[gid] = s[tid] - v;
        if (tid == 255) partials[sb] = s[255];
        __threadfence();
        if (tid == 0)
            isLast = (__hip_atomic_fetch_add(&ctl[CTL_SCNT], 1, __ATOMIC_ACQ_REL,
                                             __HIP_MEMORY_SCOPE_AGENT) == NBS - 1);
        __syncthreads();
        if (isLast) {
            __threadfence();                       // acquire: fresh partials
            int pv = (tid < NBS) ? partials[tid] : 0;
            s[tid] = pv;
            __syncthreads();
            for (int off = 1; off < 256; off <<= 1) {
                int t2 = (tid >= off) ? s[tid - off] : 0;
                __syncthreads();
                s[tid] += t2;
                __syncthreads();
            }
            if (tid < NBS) partials[tid] = s[tid] - pv;
            __threadfence();                       // release partials
            __syncthreads();
            if (tid == 0)
                __hip_atomic_store(&ctl[CTL_SFLG], 1, __ATOMIC_RELEASE, __HIP_MEMORY_SCOPE_AGENT);
        }
    } else {
        // ---------------- fill CSR (poll scan flag), grid-strided x2 ----------------
        if (tid == 0) poll_flag(&ctl[CTL_SFLG]);
        __syncthreads();
        __threadfence();                           // acquire: fresh offs/partials/dinv/cursor
        const int4* src4 = (const int4*)eidx;
        const int4* dst4 = (const int4*)(eidx + N_EDGES);
        int fb = bid - (NBG + NBC + NBS);
        for (int t = fb * 256 + tid; t < N_EDGES / 4; t += NBF * 256) {
            int4 sv = src4[t];
            int4 dv = dst4[t];
            {
                int pos = offs[dv.x] + partials[dv.x >> 8] + atomicAdd(&cursor[dv.x], 1);
                csr_sw[pos] = make_int2(sv.x, __float_as_int(dinv[sv.x]));
            }
            {
                int pos = offs[dv.y] + partials[dv.y >> 8] + atomicAdd(&cursor[dv.y], 1);
                csr_sw[pos] = make_int2(sv.y, __float_as_int(dinv[sv.y]));
            }
            {
                int pos = offs[dv.z] + partials[dv.z >> 8] + atomicAdd(&cursor[dv.z], 1);
                csr_sw[pos] = make_int2(sv.z, __float_as_int(dinv[sv.z]));
            }
            {
                int pos = offs[dv.w] + partials[dv.w >> 8] + atomicAdd(&cursor[dv.w], 1);
                csr_sw[pos] = make_int2(sv.w, __float_as_int(dinv[sv.w]));
            }
        }
    }
}

// ============ K2: agg1 (0..12499) -> agg2 (12500..15624, poll agg1 flag) ============
__global__ __launch_bounds__(256) void agg_kernel(
        const unsigned* __restrict__ Hb,
        const int2* __restrict__ csr_sw,
        const int* __restrict__ offs,
        const int* __restrict__ part,
        const float* __restrict__ dinv,
        const float4* __restrict__ fusedq,
        const float* __restrict__ W2c,
        const float* __restrict__ bc2,
        float* __restrict__ Z,
        float* __restrict__ out,
        int* __restrict__ ctl) {
    __shared__ float sH[4][128];
    int tid = threadIdx.x;
    int bid = blockIdx.x;

    if (bid < NBA1) {
        // ---------------- layer-1 agg (1 wave/node, 8-deep) + BN + ReLU + @W2c -> Z ----------------
        int w = tid >> 6, l = tid & 63;
        int node = bid * 4 + w;
        int beg = __builtin_amdgcn_readfirstlane(offs[node] + part[node >> 8]);
        int end = __builtin_amdgcn_readfirstlane(offs[node + 1] + part[(node + 1) >> 8]);
        float di = dinv[node];

        int c = l & 15, q = l >> 4;
        float wreg[32];
#pragma unroll
        for (int i = 0; i < 32; i++) wreg[i] = W2c[(q * 32 + i) * 16 + c];

        unsigned hv = Hb[(size_t)node * 64 + l];
        float n2 = di * di;
        float acc0 = bf_lo(hv) * n2, acc1 = bf_hi(hv) * n2;  // self loop

        int e = beg;
        for (; e + 8 <= end; e += 8) {
            int2 a0 = csr_sw[e];     int2 a1 = csr_sw[e + 1];
            int2 a2 = csr_sw[e + 2]; int2 a3 = csr_sw[e + 3];
            int2 a4 = csr_sw[e + 4]; int2 a5 = csr_sw[e + 5];
            int2 a6 = csr_sw[e + 6]; int2 a7 = csr_sw[e + 7];
            unsigned u0 = Hb[(size_t)a0.x * 64 + l];
            unsigned u1 = Hb[(size_t)a1.x * 64 + l];
            unsigned u2 = Hb[(size_t)a2.x * 64 + l];
            unsigned u3 = Hb[(size_t)a3.x * 64 + l];
            unsigned u4 = Hb[(size_t)a4.x * 64 + l];
            unsigned u5 = Hb[(size_t)a5.x * 64 + l];
            unsigned u6 = Hb[(size_t)a6.x * 64 + l];
            unsigned u7 = Hb[(size_t)a7.x * 64 + l];
            float w0 = __int_as_float(a0.y) * di, w1 = __int_as_float(a1.y) * di;
            float w2 = __int_as_float(a2.y) * di, w3 = __int_as_float(a3.y) * di;
            float w4 = __int_as_float(a4.y) * di, w5 = __int_as_float(a5.y) * di;
            float w6 = __int_as_float(a6.y) * di, w7 = __int_as_float(a7.y) * di;
            acc0 += bf_lo(u0) * w0 + bf_lo(u1) * w1 + bf_lo(u2) * w2 + bf_lo(u3) * w3
                  + bf_lo(u4) * w4 + bf_lo(u5) * w5 + bf_lo(u6) * w6 + bf_lo(u7) * w7;
            acc1 += bf_hi(u0) * w0 + bf_hi(u1) * w1 + bf_hi(u2) * w2 + bf_hi(u3) * w3
                  + bf_hi(u4) * w4 + bf_hi(u5) * w5 + bf_hi(u6) * w6 + bf_hi(u7) * w7;
        }
        while (e < end) {                          // masked 4-batch tail
            int i1 = e + 1 < end ? e + 1 : end - 1;
            int i2 = e + 2 < end ? e + 2 : end - 1;
            int i3 = e + 3 < end ? e + 3 : end - 1;
            int2 a0 = csr_sw[e];  int2 a1 = csr_sw[i1];
            int2 a2 = csr_sw[i2]; int2 a3 = csr_sw[i3];
            unsigned u0 = Hb[(size_t)a0.x * 64 + l];
            unsigned u1 = Hb[(size_t)a1.x * 64 + l];
            unsigned u2 = Hb[(size_t)a2.x * 64 + l];
            unsigned u3 = Hb[(size_t)a3.x * 64 + l];
            float w0 = __int_as_float(a0.y) * di;
            float w1 = (e + 1 < end) ? __int_as_float(a1.y) * di : 0.f;
            float w2 = (e + 2 < end) ? __int_as_float(a2.y) * di : 0.f;
            float w3 = (e + 3 < end) ? __int_as_float(a3.y) * di : 0.f;
            acc0 += bf_lo(u0) * w0 + bf_lo(u1) * w1 + bf_lo(u2) * w2 + bf_lo(u3) * w3;
            acc1 += bf_hi(u0) * w0 + bf_hi(u1) * w1 + bf_hi(u2) * w2 + bf_hi(u3) * w3;
            e += 4;
        }

        float4 qv = fusedq[l];
        float a0 = fmaxf(acc0 * qv.x + qv.y, 0.f);
        float a1 = fmaxf(acc1 * qv.z + qv.w, 0.f);

        ((float2*)sH[w])[l] = make_float2(a0, a1);
        float z = 0.f;
        const float4* row4 = (const float4*)&sH[w][q * 32];
#pragma unroll
        for (int i = 0; i < 8; i++) {
            float4 v = row4[i];
            z += v.x * wreg[i * 4] + v.y * wreg[i * 4 + 1]
               + v.z * wreg[i * 4 + 2] + v.w * wreg[i * 4 + 3];
        }
        z += __shfl_xor(z, 16);
        z += __shfl_xor(z, 32);
        if (l < 16) Z[(size_t)node * NCLS + l] = z;
        finish_stage(&ctl[CTL_ACNT], &ctl[CTL_AFLG], NBA1, tid);
    } else {
        // ---------------- layer-2 agg on Z (16-wide) + bc2 -> out ----------------
        if (tid == 0) poll_flag(&ctl[CTL_AFLG]);
        __syncthreads();
        __threadfence();                           // acquire: fresh Z
        int grp = tid >> 4, c = tid & 15;
        int node = (bid - NBA1) * 16 + grp;
        int beg = offs[node] + part[node >> 8];
        int end = offs[node + 1] + part[(node + 1) >> 8];
        float di = dinv[node];

        float acc = Z[(size_t)node * NCLS + c] * di * di;
        int e = beg;
        for (; e + 8 <= end; e += 8) {
            int2 a0 = csr_sw[e],     a1 = csr_sw[e + 1];
            int2 a2 = csr_sw[e + 2], a3 = csr_sw[e + 3];
            int2 a4 = csr_sw[e + 4], a5 = csr_sw[e + 5];
            int2 a6 = csr_sw[e + 6], a7 = csr_sw[e + 7];
            float v0 = Z[(size_t)a0.x * NCLS + c];
            float v1 = Z[(size_t)a1.x * NCLS + c];
            float v2 = Z[(size_t)a2.x * NCLS + c];
            float v3 = Z[(size_t)a3.x * NCLS + c];
            float v4 = Z[(size_t)a4.x * NCLS + c];
            float v5 = Z[(size_t)a5.x * NCLS + c];
            float v6 = Z[(size_t)a6.x * NCLS + c];
            float v7 = Z[(size_t)a7.x * NCLS + c];
            acc += v0 * (__int_as_float(a0.y) * di) + v1 * (__int_as_float(a1.y) * di)
                 + v2 * (__int_as_float(a2.y) * di) + v3 * (__int_as_float(a3.y) * di)
                 + v4 * (__int_as_float(a4.y) * di) + v5 * (__int_as_float(a5.y) * di)
                 + v6 * (__int_as_float(a6.y) * di) + v7 * (__int_as_float(a7.y) * di);
        }
        for (; e < end; e++) {
            int2 a = csr_sw[e];
            acc += Z[(size_t)a.x * NCLS + c] * (__int_as_float(a.y) * di);
        }
        out[(size_t)node * NCLS + c] = acc + bc2[c];
    }
}

// ---------------- Launch: 3 dispatches ----------------
extern "C" void kernel_launch(void* const* d_in, const int* in_sizes, int n_in,
                              void* d_out, int out_size, void* d_ws, size_t ws_size,
                              hipStream_t stream) {
    const float* seq   = (const float*)d_in[0];
    const int*   eidx  = (const int*)d_in[1];
    const float* W1    = (const float*)d_in[2];
    const float* b1    = (const float*)d_in[3];
    const float* gamma = (const float*)d_in[4];
    const float* beta  = (const float*)d_in[5];
    const float* rmean = (const float*)d_in[6];
    const float* rvar  = (const float*)d_in[7];
    const float* W2    = (const float*)d_in[8];
    const float* b2    = (const float*)d_in[9];
    const float* Wc    = (const float*)d_in[10];
    const float* bc    = (const float*)d_in[11];

    char* ws = (char*)d_ws;
    size_t off = 0;
    auto alloc = [&](size_t bytes) -> void* {
        void* p = ws + off;
        off = (off + bytes + 255) & ~(size_t)255;
        return p;
    };
    int*    ctl      = (int*)alloc(1024);          // 256 ints; flags on separate 128B lines
    int*    deg      = (int*)alloc(N_NODES * 4);
    int*    cursor   = (int*)alloc(N_NODES * 4);
    int*    offs     = (int*)alloc((N_NODES + 1) * 4);
    int*    partials = (int*)alloc(256 * 4);
    float*  dinv     = (float*)alloc(N_NODES * 4);
    int2*   csr_sw   = (int2*)alloc((size_t)N_EDGES * 8);
    float*  W2c      = (float*)alloc(FDIM * NCLS * 4);
    float*  bc2      = (float*)alloc(NCLS * 4);
    float4* fusedq   = (float4*)alloc(64 * 16);
    bf16x8* WHg      = (bf16x8*)alloc(2048 * 16);
    bf16x8* WLg      = (bf16x8*)alloc(2048 * 16);
    unsigned* bufA   = (unsigned*)alloc((size_t)N_NODES * (FDIM / 2) * 4);
    float*  Zbuf     = (float*)alloc((size_t)N_NODES * NCLS * 4);

    packw_fold_zero_kernel<<<16, 256, 0, stream>>>(W1, W2, Wc, b1, b2, bc, gamma, beta,
                                                   rmean, rvar, WHg, WLg, W2c, bc2, fusedq,
                                                   deg, ctl);
    gemm_csr_kernel<<<NBG + NBC + NBS + NBF, 256, 0, stream>>>(
        seq, WHg, WLg, bufA, eidx, deg, cursor, offs, partials, dinv, csr_sw, ctl);
    agg_kernel<<<NBA1 + NBA2, 256, 0, stream>>>(bufA, csr_sw, offs, partials, dinv,
                                                fusedq, W2c, bc2, Zbuf, (float*)d_out, ctl);
}

// Round 13
// 234.105 us; speedup vs baseline: 7.6029x; 7.6029x over previous
//
#include <hip/hip_runtime.h>
#include <math.h>

#define N_NODES 50000
#define N_EDGES 640000
#define FDIM 128
#define NCLS 16
#define BN_EPS 1e-5f
#define NBS 196           // scan blocks
#define NBG 782           // gemm tiles

typedef __attribute__((ext_vector_type(8))) short bf16x8;
typedef __attribute__((ext_vector_type(4))) float f32x4;

// ---- bf16 pack/unpack (RNE) ----
__device__ __forceinline__ unsigned pack_bf16x2(float lo, float hi) {
    unsigned ul = __float_as_uint(lo);
    unsigned uh = __float_as_uint(hi);
    ul += 0x7fff + ((ul >> 16) & 1);
    uh += 0x7fff + ((uh >> 16) & 1);
    return (ul >> 16) | (uh & 0xffff0000u);
}
__device__ __forceinline__ unsigned short bf16_rne(float x) {
    unsigned u = __float_as_uint(x);
    u += 0x7fff + ((u >> 16) & 1);
    return (unsigned short)(u >> 16);
}
__device__ __forceinline__ float bf_lo(unsigned u) { return __uint_as_float(u << 16); }
__device__ __forceinline__ float bf_hi(unsigned u) { return __uint_as_float(u & 0xffff0000u); }

// ============ K0: fold (0..7) | W1 hi/lo pack (8..15) | zero deg+ctl (replaces memset) ============
__global__ __launch_bounds__(256) void packw_fold_zero_kernel(
        const float* __restrict__ W1,
        const float* __restrict__ W2, const float* __restrict__ Wc,
        const float* __restrict__ b1, const float* __restrict__ b2,
        const float* __restrict__ bc, const float* __restrict__ gamma,
        const float* __restrict__ beta, const float* __restrict__ rmean,
        const float* __restrict__ rvar,
        bf16x8* __restrict__ WHg, bf16x8* __restrict__ WLg,
        float* __restrict__ W2c, float* __restrict__ bc2, float4* __restrict__ fusedq,
        int* __restrict__ deg, int* __restrict__ ctl) {
    int tid = threadIdx.x;
    int bid = blockIdx.x;
    for (int i = bid * 256 + tid; i < N_NODES; i += 16 * 256) deg[i] = 0;
    if (bid == 0) ctl[tid] = 0;

    if (bid < 8) {
        int gid = bid * 256 + tid;                 // 0..2047
        int r = gid >> 4, c = gid & 15;
        float acc = 0.f;
#pragma unroll 8
        for (int k = 0; k < 128; k++) acc += W2[r * 128 + k] * Wc[k * 16 + c];
        W2c[gid] = acc;
        if (bid == 0) {
            if (tid < 16) {
                float a = bc[tid];
                for (int k = 0; k < 128; k++) a += b2[k] * Wc[k * 16 + tid];
                bc2[tid] = a;
            }
            if (tid < 64) {
                int c0 = tid * 2, c1 = c0 + 1;
                float sc0 = gamma[c0] * rsqrtf(rvar[c0] + BN_EPS);
                float sc1 = gamma[c1] * rsqrtf(rvar[c1] + BN_EPS);
                float sh0 = (b1[c0] - rmean[c0]) * sc0 + beta[c0];
                float sh1 = (b1[c1] - rmean[c1]) * sc1 + beta[c1];
                fusedq[tid] = make_float4(sc0, sh0, sc1, sh1);
            }
        }
    } else {
        int fi = (bid - 8) * 256 + tid;            // fragment index 0..2047
        int lane = fi & 63, kt = (fi >> 6) & 3, ct = fi >> 8;
        int kbase = kt * 32 + (lane >> 4) * 8;
        int col = ct * 16 + (lane & 15);
        short h[8], lo[8];
#pragma unroll
        for (int j = 0; j < 8; j++) {
            float wv = W1[(kbase + j) * 128 + col];
            unsigned short hs = bf16_rne(wv);
            float rem = wv - __uint_as_float(((unsigned)hs) << 16);
            h[j] = (short)hs;
            lo[j] = (short)bf16_rne(rem);
        }
        WHg[fi] = *(bf16x8*)h;
        WLg[fi] = *(bf16x8*)lo;
    }
}

// ============ K1: MFMA gemm (blocks 0..781) | count_deg (782..1406) ============
__global__ __launch_bounds__(256) void gemm_count_kernel(
        const float* __restrict__ seq,
        const bf16x8* __restrict__ WHg, const bf16x8* __restrict__ WLg,
        unsigned* __restrict__ bufA,
        const int* __restrict__ eidx, int* __restrict__ deg) {
    __shared__ __align__(16) float sC[64 * 132];   // 33.8 KB -> 4 blocks/CU
    int tid = threadIdx.x;
    int bid = blockIdx.x;

    if (bid < NBG) {
        int w = tid >> 6, l = tid & 63;
        int la = l & 15, q = l >> 4;
        int r0 = bid * 64;
        int arow = r0 + w * 16 + la;
        bool rowok = arow < N_NODES;
        const float4* X4 = (const float4*)seq;

        float4 xr[8];
#pragma unroll
        for (int kt = 0; kt < 4; kt++) {
            float4 z4 = make_float4(0.f, 0.f, 0.f, 0.f);
            xr[kt * 2]     = rowok ? X4[arow * 32 + kt * 8 + q * 2]     : z4;
            xr[kt * 2 + 1] = rowok ? X4[arow * 32 + kt * 8 + q * 2 + 1] : z4;
        }
        bf16x8 ah[4], al[4];
#pragma unroll
        for (int kt = 0; kt < 4; kt++) {
            const float* xv = (const float*)&xr[kt * 2];
#pragma unroll
            for (int j = 0; j < 8; j++) {
                float v = xv[j];
                unsigned short hs = bf16_rne(v);
                float rem = v - __uint_as_float(((unsigned)hs) << 16);
                ah[kt][j] = (short)hs;
                al[kt][j] = (short)bf16_rne(rem);
            }
        }
        f32x4 acc[8];
#pragma unroll
        for (int ct = 0; ct < 8; ct++) acc[ct] = (f32x4){0.f, 0.f, 0.f, 0.f};
#pragma unroll
        for (int kt = 0; kt < 4; kt++) {
#pragma unroll
            for (int ct = 0; ct < 8; ct++) {
                bf16x8 bh = WHg[(ct * 4 + kt) * 64 + l];   // coalesced b128, L2-hot
                bf16x8 bl = WLg[(ct * 4 + kt) * 64 + l];
                acc[ct] = __builtin_amdgcn_mfma_f32_16x16x32_bf16(ah[kt], bh, acc[ct], 0, 0, 0);
                acc[ct] = __builtin_amdgcn_mfma_f32_16x16x32_bf16(ah[kt], bl, acc[ct], 0, 0, 0);
                acc[ct] = __builtin_amdgcn_mfma_f32_16x16x32_bf16(al[kt], bh, acc[ct], 0, 0, 0);
            }
        }
        // repack C through LDS -> bf16 bufA (b128 reads: 2-way alias = free)
#pragma unroll
        for (int ct = 0; ct < 8; ct++)
#pragma unroll
            for (int r = 0; r < 4; r++)
                sC[(w * 16 + q * 4 + r) * 132 + ct * 16 + la] = acc[ct][r];
        __syncthreads();
        int trow = tid >> 2, tcb = (tid & 3) * 32;
        int grow = r0 + trow;
        if (grow < N_NODES) {
            const float4* sr4 = (const float4*)(sC + trow * 132 + tcb);
            unsigned ob[16];
#pragma unroll
            for (int t = 0; t < 8; t++) {
                float4 v = sr4[t];
                ob[2 * t]     = pack_bf16x2(v.x, v.y);
                ob[2 * t + 1] = pack_bf16x2(v.z, v.w);
            }
            uint4* dp = (uint4*)(bufA + (size_t)grow * 64 + (tid & 3) * 16);
#pragma unroll
            for (int g = 0; g < 4; g++)
                dp[g] = make_uint4(ob[g * 4], ob[g * 4 + 1], ob[g * 4 + 2], ob[g * 4 + 3]);
        }
    } else {
        // -------- count in-degrees: 4 edges/thread, int4 reads --------
        const int4* dst4 = (const int4*)(eidx + N_EDGES);
        int t = (bid - NBG) * 256 + tid;
        int4 d = dst4[t];
        atomicAdd(&deg[d.x], 1);
        atomicAdd(&deg[d.y], 1);
        atomicAdd(&deg[d.z], 1);
        atomicAdd(&deg[d.w], 1);
    }
}

// ============ K2: block-local scan + dinv + cursor zero; LAST block scans partials ============
__global__ __launch_bounds__(256) void scan_kernel(const int* __restrict__ deg,
                                                   int* __restrict__ offs,
                                                   int* __restrict__ partials,
                                                   float* __restrict__ dinv,
                                                   int* __restrict__ cursor,
                                                   int* __restrict__ done) {
    __shared__ int s[256];
    __shared__ int isLast;
    int tid = threadIdx.x;
    int gid = blockIdx.x * 256 + tid;
    int v = (gid < N_NODES) ? deg[gid] : 0;
    if (gid < N_NODES) {
        dinv[gid] = rsqrtf((float)(v + 1));  // +1 self loop
        cursor[gid] = 0;
    }
    s[tid] = v;
    __syncthreads();
    for (int off = 1; off < 256; off <<= 1) {
        int t2 = (tid >= off) ? s[tid - off] : 0;
        __syncthreads();
        s[tid] += t2;
        __syncthreads();
    }
    if (gid <= N_NODES) offs[gid] = s[tid] - v;   // block-local exclusive
    if (tid == 255) partials[blockIdx.x] = s[255];

    __threadfence();                               // publish partials[bid] device-wide
    if (tid == 0) isLast = (atomicAdd(done, 1) == NBS - 1);
    __syncthreads();
    if (isLast) {
        __threadfence();                           // acquire all partials
        int pv = (tid < NBS) ? partials[tid] : 0;
        s[tid] = pv;
        __syncthreads();
        for (int off = 1; off < 256; off <<= 1) {
            int t2 = (tid >= off) ? s[tid - off] : 0;
            __syncthreads();
            s[tid] += t2;
            __syncthreads();
        }
        if (tid < NBS) partials[tid] = s[tid] - pv;  // exclusive totals
    }
}

// ============ K3: fill CSR (4 edges/thread) ============
__global__ __launch_bounds__(256) void fill_csr_kernel(const int* __restrict__ eidx,
                                                       const int* __restrict__ offs,
                                                       const int* __restrict__ part,
                                                       const float* __restrict__ dinv,
                                                       int* __restrict__ cursor,
                                                       int2* __restrict__ csr_sw) {
    const int4* src4 = (const int4*)eidx;
    const int4* dst4 = (const int4*)(eidx + N_EDGES);
    int t = blockIdx.x * 256 + threadIdx.x;
    int4 sv = src4[t];
    int4 dv = dst4[t];
    {
        int pos = offs[dv.x] + part[dv.x >> 8] + atomicAdd(&cursor[dv.x], 1);
        csr_sw[pos] = make_int2(sv.x, __float_as_int(dinv[sv.x]));
    }
    {
        int pos = offs[dv.y] + part[dv.y >> 8] + atomicAdd(&cursor[dv.y], 1);
        csr_sw[pos] = make_int2(sv.y, __float_as_int(dinv[sv.y]));
    }
    {
        int pos = offs[dv.z] + part[dv.z >> 8] + atomicAdd(&cursor[dv.z], 1);
        csr_sw[pos] = make_int2(sv.z, __float_as_int(dinv[sv.z]));
    }
    {
        int pos = offs[dv.w] + part[dv.w >> 8] + atomicAdd(&cursor[dv.w], 1);
        csr_sw[pos] = make_int2(sv.w, __float_as_int(dinv[sv.w]));
    }
}

// ============ K4: layer-1 agg (1 wave/node, 8-deep) + BN + ReLU + @W2c -> Z ============
__global__ __launch_bounds__(256) void agg1_kernel(const unsigned* __restrict__ Hb,
                                                   const int2* __restrict__ csr_sw,
                                                   const int* __restrict__ offs,
                                                   const int* __restrict__ part,
                                                   const float* __restrict__ dinv,
                                                   const float4* __restrict__ fusedq,
                                                   const float* __restrict__ W2c,
                                                   float* __restrict__ Z) {
    __shared__ float sH[4][128];
    int w = threadIdx.x >> 6, l = threadIdx.x & 63;
    int node = blockIdx.x * 4 + w;             // 12500*4 == 50000
    int beg = __builtin_amdgcn_readfirstlane(offs[node] + part[node >> 8]);
    int end = __builtin_amdgcn_readfirstlane(offs[node + 1] + part[(node + 1) >> 8]);
    float di = dinv[node];

    int c = l & 15, q = l >> 4;
    float wreg[32];
#pragma unroll
    for (int i = 0; i < 32; i++) wreg[i] = W2c[(q * 32 + i) * 16 + c];

    unsigned hv = Hb[(size_t)node * 64 + l];
    float n2 = di * di;
    float acc0 = bf_lo(hv) * n2, acc1 = bf_hi(hv) * n2;  // self loop

    int e = beg;
    for (; e + 8 <= end; e += 8) {             // 8 full-wave row loads in flight
        int2 a0 = csr_sw[e];     int2 a1 = csr_sw[e + 1];
        int2 a2 = csr_sw[e + 2]; int2 a3 = csr_sw[e + 3];
        int2 a4 = csr_sw[e + 4]; int2 a5 = csr_sw[e + 5];
        int2 a6 = csr_sw[e + 6]; int2 a7 = csr_sw[e + 7];
        unsigned u0 = Hb[(size_t)a0.x * 64 + l];
        unsigned u1 = Hb[(size_t)a1.x * 64 + l];
        unsigned u2 = Hb[(size_t)a2.x * 64 + l];
        unsigned u3 = Hb[(size_t)a3.x * 64 + l];
        unsigned u4 = Hb[(size_t)a4.x * 64 + l];
        unsigned u5 = Hb[(size_t)a5.x * 64 + l];
        unsigned u6 = Hb[(size_t)a6.x * 64 + l];
        unsigned u7 = Hb[(size_t)a7.x * 64 + l];
        float w0 = __int_as_float(a0.y) * di, w1 = __int_as_float(a1.y) * di;
        float w2 = __int_as_float(a2.y) * di, w3 = __int_as_float(a3.y) * di;
        float w4 = __int_as_float(a4.y) * di, w5 = __int_as_float(a5.y) * di;
        float w6 = __int_as_float(a6.y) * di, w7 = __int_as_float(a7.y) * di;
        acc0 += bf_lo(u0) * w0 + bf_lo(u1) * w1 + bf_lo(u2) * w2 + bf_lo(u3) * w3
              + bf_lo(u4) * w4 + bf_lo(u5) * w5 + bf_lo(u6) * w6 + bf_lo(u7) * w7;
        acc1 += bf_hi(u0) * w0 + bf_hi(u1) * w1 + bf_hi(u2) * w2 + bf_hi(u3) * w3
              + bf_hi(u4) * w4 + bf_hi(u5) * w5 + bf_hi(u6) * w6 + bf_hi(u7) * w7;
    }
    while (e < end) {                          // masked 4-batch tail (parallel loads)
        int i1 = e + 1 < end ? e + 1 : end - 1;
        int i2 = e + 2 < end ? e + 2 : end - 1;
        int i3 = e + 3 < end ? e + 3 : end - 1;
        int2 a0 = csr_sw[e];  int2 a1 = csr_sw[i1];
        int2 a2 = csr_sw[i2]; int2 a3 = csr_sw[i3];
        unsigned u0 = Hb[(size_t)a0.x * 64 + l];
        unsigned u1 = Hb[(size_t)a1.x * 64 + l];
        unsigned u2 = Hb[(size_t)a2.x * 64 + l];
        unsigned u3 = Hb[(size_t)a3.x * 64 + l];
        float w0 = __int_as_float(a0.y) * di;
        float w1 = (e + 1 < end) ? __int_as_float(a1.y) * di : 0.f;
        float w2 = (e + 2 < end) ? __int_as_float(a2.y) * di : 0.f;
        float w3 = (e + 3 < end) ? __int_as_float(a3.y) * di : 0.f;
        acc0 += bf_lo(u0) * w0 + bf_lo(u1) * w1 + bf_lo(u2) * w2 + bf_lo(u3) * w3;
        acc1 += bf_hi(u0) * w0 + bf_hi(u1) * w1 + bf_hi(u2) * w2 + bf_hi(u3) * w3;
        e += 4;
    }

    float4 qv = fusedq[l];
    float a0 = fmaxf(acc0 * qv.x + qv.y, 0.f);
    float a1 = fmaxf(acc1 * qv.z + qv.w, 0.f);

    ((float2*)sH[w])[l] = make_float2(a0, a1);
    float z = 0.f;
    const float4* row4 = (const float4*)&sH[w][q * 32];
#pragma unroll
    for (int i = 0; i < 8; i++) {
        float4 v = row4[i];
        z += v.x * wreg[i * 4] + v.y * wreg[i * 4 + 1]
           + v.z * wreg[i * 4 + 2] + v.w * wreg[i * 4 + 3];
    }
    z += __shfl_xor(z, 16);
    z += __shfl_xor(z, 32);
    if (l < 16) Z[(size_t)node * NCLS + l] = z;
}

// ============ K5: layer-2 agg on Z (16-wide) + bc2 -> out ============
__global__ __launch_bounds__(256) void agg2_kernel(const float* __restrict__ Z,
                                                   const int2* __restrict__ csr_sw,
                                                   const int* __restrict__ offs,
                                                   const int* __restrict__ part,
                                                   const float* __restrict__ dinv,
                                                   const float* __restrict__ bc2,
                                                   float* __restrict__ out) {
    int grp = threadIdx.x >> 4, c = threadIdx.x & 15;
    int node = blockIdx.x * 16 + grp;          // 3125*16 == 50000
    int beg = offs[node] + part[node >> 8];
    int end = offs[node + 1] + part[(node + 1) >> 8];
    float di = dinv[node];

    float acc = Z[(size_t)node * NCLS + c] * di * di;
    int e = beg;
    for (; e + 8 <= end; e += 8) {
        int2 a0 = csr_sw[e],     a1 = csr_sw[e + 1];
        int2 a2 = csr_sw[e + 2], a3 = csr_sw[e + 3];
        int2 a4 = csr_sw[e + 4], a5 = csr_sw[e + 5];
        int2 a6 = csr_sw[e + 6], a7 = csr_sw[e + 7];
        float v0 = Z[(size_t)a0.x * NCLS + c];
        float v1 = Z[(size_t)a1.x * NCLS + c];
        float v2 = Z[(size_t)a2.x * NCLS + c];
        float v3 = Z[(size_t)a3.x * NCLS + c];
        float v4 = Z[(size_t)a4.x * NCLS + c];
        float v5 = Z[(size_t)a5.x * NCLS + c];
        float v6 = Z[(size_t)a6.x * NCLS + c];
        float v7 = Z[(size_t)a7.x * NCLS + c];
        acc += v0 * (__int_as_float(a0.y) * di) + v1 * (__int_as_float(a1.y) * di)
             + v2 * (__int_as_float(a2.y) * di) + v3 * (__int_as_float(a3.y) * di)
             + v4 * (__int_as_float(a4.y) * di) + v5 * (__int_as_float(a5.y) * di)
             + v6 * (__int_as_float(a6.y) * di) + v7 * (__int_as_float(a7.y) * di);
    }
    for (; e < end; e++) {
        int2 a = csr_sw[e];
        acc += Z[(size_t)a.x * NCLS + c] * (__int_as_float(a.y) * di);
    }
    out[(size_t)node * NCLS + c] = acc + bc2[c];
}

// ---------------- Launch: 6 dispatches, no memset, no spin-sync ----------------
extern "C" void kernel_launch(void* const* d_in, const int* in_sizes, int n_in,
                              void* d_out, int out_size, void* d_ws, size_t ws_size,
                              hipStream_t stream) {
    const float* seq   = (const float*)d_in[0];
    const int*   eidx  = (const int*)d_in[1];
    const float* W1    = (const float*)d_in[2];
    const float* b1    = (const float*)d_in[3];
    const float* gamma = (const float*)d_in[4];
    const float* beta  = (const float*)d_in[5];
    const float* rmean = (const float*)d_in[6];
    const float* rvar  = (const float*)d_in[7];
    const float* W2    = (const float*)d_in[8];
    const float* b2    = (const float*)d_in[9];
    const float* Wc    = (const float*)d_in[10];
    const float* bc    = (const float*)d_in[11];

    char* ws = (char*)d_ws;
    size_t off = 0;
    auto alloc = [&](size_t bytes) -> void* {
        void* p = ws + off;
        off = (off + bytes + 255) & ~(size_t)255;
        return p;
    };
    int*    ctl      = (int*)alloc(1024);
    int*    deg      = (int*)alloc(N_NODES * 4);
    int*    cursor   = (int*)alloc(N_NODES * 4);
    int*    offs     = (int*)alloc((N_NODES + 1) * 4);
    int*    partials = (int*)alloc(256 * 4);
    float*  dinv     = (float*)alloc(N_NODES * 4);
    int2*   csr_sw   = (int2*)alloc((size_t)N_EDGES * 8);
    float*  W2c      = (float*)alloc(FDIM * NCLS * 4);
    float*  bc2      = (float*)alloc(NCLS * 4);
    float4* fusedq   = (float4*)alloc(64 * 16);
    bf16x8* WHg      = (bf16x8*)alloc(2048 * 16);
    bf16x8* WLg      = (bf16x8*)alloc(2048 * 16);
    unsigned* bufA   = (unsigned*)alloc((size_t)N_NODES * (FDIM / 2) * 4);
    float*  Zbuf     = (float*)alloc((size_t)N_NODES * NCLS * 4);

    packw_fold_zero_kernel<<<16, 256, 0, stream>>>(W1, W2, Wc, b1, b2, bc, gamma, beta,
                                                   rmean, rvar, WHg, WLg, W2c, bc2, fusedq,
                                                   deg, ctl);
    gemm_count_kernel<<<NBG + 625, 256, 0, stream>>>(seq, WHg, WLg, bufA, eidx, deg);
    scan_kernel<<<NBS, 256, 0, stream>>>(deg, offs, partials, dinv, cursor, ctl);
    fill_csr_kernel<<<625, 256, 0, stream>>>(eidx, offs, partials, dinv, cursor, csr_sw);
    agg1_kernel<<<N_NODES / 4, 256, 0, stream>>>(bufA, csr_sw, offs, partials,
                                                 dinv, fusedq, W2c, Zbuf);
    agg2_kernel<<<N_NODES / 16, 256, 0, stream>>>(Zbuf, csr_sw, offs, partials,
                                                  dinv, bc2, (float*)d_out);
}